// Round 13
// baseline (962.880 us; speedup 1.0000x reference)
//
#include <hip/hip_runtime.h>
#include <cstdint>

#define NB   4      // batches
#define NPT  8192   // points
#define NC   256    // feature channels
#define NS   1024   // FPS samples
#define NK   64     // neighbors per ball
#define FPT  32     // points per thread in FPS (8192 / 256 threads)

typedef float v2f __attribute__((ext_vector_type(2)));

// ---------------------------------------------------------------------------
// Packed-FP32 distance block: TWO v2f iterations per asm statement.
// r10's per-op pk asm lost its win to operand-copy movs; batching 16 pk ops
// with block-local temps amortizes register-pair setup to zero.
// Math per element (EXACT reference order, VERIFIED r1-r12):
//   dx = px + (-sx); dy, dz likewise   (IEEE: a + (-b) == a - b, exact)
//   d  = ((dx*dx + dy*dy) + dz*dz)     (no FMA — pk_mul/pk_add can't fuse)
// ---------------------------------------------------------------------------
#define DIST2(J0, J1, D0, D1)                                              \
  {                                                                        \
    v2f t0, t1, t2, u0, u1, u2;                                            \
    asm("v_pk_add_f32 %[T0], %[PX0], %[NSX]\n\t"                           \
        "v_pk_add_f32 %[T1], %[PY0], %[NSY]\n\t"                           \
        "v_pk_add_f32 %[T2], %[PZ0], %[NSZ]\n\t"                           \
        "v_pk_add_f32 %[U0], %[PX1], %[NSX]\n\t"                           \
        "v_pk_add_f32 %[U1], %[PY1], %[NSY]\n\t"                           \
        "v_pk_add_f32 %[U2], %[PZ1], %[NSZ]\n\t"                           \
        "v_pk_mul_f32 %[T0], %[T0], %[T0]\n\t"                             \
        "v_pk_mul_f32 %[T1], %[T1], %[T1]\n\t"                             \
        "v_pk_mul_f32 %[T2], %[T2], %[T2]\n\t"                             \
        "v_pk_mul_f32 %[U0], %[U0], %[U0]\n\t"                             \
        "v_pk_mul_f32 %[U1], %[U1], %[U1]\n\t"                             \
        "v_pk_mul_f32 %[U2], %[U2], %[U2]\n\t"                             \
        "v_pk_add_f32 %[T0], %[T0], %[T1]\n\t"                             \
        "v_pk_add_f32 %[U0], %[U0], %[U1]\n\t"                             \
        "v_pk_add_f32 %[T0], %[T0], %[T2]\n\t"                             \
        "v_pk_add_f32 %[U0], %[U0], %[U2]"                                 \
        : [T0] "=&v"(t0), [T1] "=&v"(t1), [T2] "=&v"(t2),                  \
          [U0] "=&v"(u0), [U1] "=&v"(u1), [U2] "=&v"(u2)                   \
        : [PX0] "v"(px[J0]), [PY0] "v"(py[J0]), [PZ0] "v"(pz[J0]),         \
          [PX1] "v"(px[J1]), [PY1] "v"(py[J1]), [PZ1] "v"(pz[J1]),         \
          [NSX] "v"(nsxv), [NSY] "v"(nsyv), [NSZ] "v"(nszv));              \
    D0 = t0; D1 = u0;                                                      \
  }

// ---------------------------------------------------------------------------
// DPP max step (f32, old=0 fill — safe: all reduced values >= 0).
// ---------------------------------------------------------------------------
template <int CTRL, int RMASK>
__device__ __forceinline__ float dpp_max_step(float x) {
    const int t = __builtin_amdgcn_update_dpp(
        0, __float_as_int(x), CTRL, RMASK, 0xf, false);
    return fmaxf(x, __int_as_float(t));
}
__device__ __forceinline__ float wave_max_f32(float x) {
    x = dpp_max_step<0x111, 0xf>(x);  // row_shr:1
    x = dpp_max_step<0x112, 0xf>(x);  // row_shr:2
    x = dpp_max_step<0x114, 0xf>(x);  // row_shr:4
    x = dpp_max_step<0x118, 0xf>(x);  // row_shr:8
    x = dpp_max_step<0x142, 0xa>(x);  // row_bcast:15 -> rows 1,3
    x = dpp_max_step<0x143, 0xc>(x);  // row_bcast:31 -> rows 2,3
    return x;                          // lane 63 holds wave max
}

// ---------------------------------------------------------------------------
// Kernel 1: farthest point sampling. One 256-thread block (4 waves = 1 per
// SIMD) per batch. Structure/handshake = round 7 VERBATIM (815 µs empirical
// best; r8-r12 alternatives all regressed). Single change: the 16 distance
// computations per step run as forced v_pk_*_f32 via 8 DIST2 asm blocks
// (clang scalarizes v2f arithmetic otherwise — r9 proxy evidence), halving
// the arithmetic instruction count. min/max/first-occurrence tracking stays
// scalar & verbatim (no packed f32 min/max exists on gfx950).
// Handshake (VERIFIED r5/r7): delegate atomicMax's packed u64 key
// (valbits<<32 | 0xFFFFFFFF-idx) into a 3-slot rotating LDS buffer;
// post-barrier broadcast ds_read_b64; centroid re-fetch via 3 uniform b32
// reads. 3-slot zeroing proof: slot[nxt] was last read at step s-2
// post-barrier, before barrier(s-1), before tid0's zeroing at step s; the
// zero is ordered before step s+1's atomics by barrier(s). No race.
// First-occurrence argmax (VERIFIED r1-r12): x-half = tid*32+0..15, y-half
// = tid*32+16..31; strict-> per half keeps earliest index; combine prefers
// x; lowest achieving lane via ballot+ffs; cross-wave via key max.
// ---------------------------------------------------------------------------
__global__ __launch_bounds__(256, 1) void fps_kernel(
    const float* __restrict__ xyz, float* __restrict__ sample_xyz)
{
    const int b   = blockIdx.x;
    const int tid = threadIdx.x;

    __shared__ float Xs[NPT], Ys[NPT], Zs[NPT];        // 96 KB SoA copy
    __shared__ float Samp[NS * 3];                     // 12 KB result buffer
    __shared__ unsigned long long slots[3];            // rotating winner slots

    const float* base = xyz + (size_t)b * NPT * 3;

    v2f px[16], py[16], pz[16], md[16];
#pragma unroll
    for (int j = 0; j < 16; ++j) {
        const int pa = tid * FPT + j;         // x-half point
        const int pb = tid * FPT + 16 + j;    // y-half point
        const float ax = base[pa * 3 + 0], ay = base[pa * 3 + 1], az = base[pa * 3 + 2];
        const float bx = base[pb * 3 + 0], by = base[pb * 3 + 1], bz = base[pb * 3 + 2];
        px[j] = (v2f){ax, bx};
        py[j] = (v2f){ay, by};
        pz[j] = (v2f){az, bz};
        md[j] = (v2f){__builtin_inff(), __builtin_inff()};
        Xs[pa] = ax; Ys[pa] = ay; Zs[pa] = az;
        Xs[pb] = bx; Ys[pb] = by; Zs[pb] = bz;
    }
    if (tid < 3) slots[tid] = 0ull;
    __syncthreads();

    int widx = 0;           // deterministic start at index 0 (matches reference)
    int cur = 0, nxt = 1;   // rotating slot indices
    for (int s = 0; s < NS; ++s) {
        // centroid xyz: uniform-address LDS broadcast reads (b32, conflict-free)
        const float sx = Xs[widx];
        const float sy = Ys[widx];
        const float sz = Zs[widx];
        if (tid == 0) {
            Samp[s * 3 + 0] = sx; Samp[s * 3 + 1] = sy; Samp[s * 3 + 2] = sz;
            slots[nxt] = 0ull;   // safe per 3-slot proof above
        }

        // negate once per step: pk_add(p, -c) == p - c bit-exactly
        const v2f nsxv = (v2f){-sx, -sx};
        const v2f nsyv = (v2f){-sy, -sy};
        const v2f nszv = (v2f){-sz, -sz};

        // ---- distances: 8 packed asm blocks (2 v2f iterations each) ----
        v2f dd[16];
        DIST2( 0,  1, dd[ 0], dd[ 1]);
        DIST2( 2,  3, dd[ 2], dd[ 3]);
        DIST2( 4,  5, dd[ 4], dd[ 5]);
        DIST2( 6,  7, dd[ 6], dd[ 7]);
        DIST2( 8,  9, dd[ 8], dd[ 9]);
        DIST2(10, 11, dd[10], dd[11]);
        DIST2(12, 13, dd[12], dd[13]);
        DIST2(14, 15, dd[14], dd[15]);

        // ---- min/max/track: scalar, VERBATIM r7 semantics ----
        v2f best2 = (v2f){-1.0f, -1.0f};
        int jx = 0, jy = 0;
#pragma unroll
        for (int j = 0; j < 16; ++j) {
            const v2f m = __builtin_elementwise_min(md[j], dd[j]);
            md[j] = m;
            // strict > keeps first occurrence within each half
            if (m.x > best2.x) jx = j;
            if (m.y > best2.y) jy = j;
            best2 = __builtin_elementwise_max(best2, m);
        }
        // combine halves: every x-half index < every y-half index
        float    bestval;
        unsigned bestidx;
        if (best2.y > best2.x) { bestval = best2.y; bestidx = (unsigned)(tid * FPT + 16 + jy); }
        else                   { bestval = best2.x; bestidx = (unsigned)(tid * FPT + jx); }

        // wave max via DPP (VALU pipe), then first achieving lane via ballot
        const float wmax = wave_max_f32(bestval);
        const float smax = __int_as_float(
            __builtin_amdgcn_readlane(__float_as_int(wmax), 63));
        const unsigned long long msk = __ballot(bestval == smax);
        const int wl = __ffsll((long long)msk) - 1;          // lowest lane
        const unsigned widx_w =
            (unsigned)__builtin_amdgcn_readlane((int)bestidx, wl);
        if ((tid & 63) == 0) {
            const unsigned long long key =
                ((unsigned long long)__float_as_uint(smax) << 32)
                | (unsigned long long)(0xFFFFFFFFu - widx_w);
            atomicMax(&slots[cur], key);     // ds_max_u64, fire-and-forget
        }
        __syncthreads();

        // broadcast read of the winning key (b64 uniform — cheap)
        const unsigned long long best = slots[cur];
        widx = (int)(0xFFFFFFFFu - (unsigned)(best & 0xFFFFFFFFull));
        cur = nxt;
        nxt = (nxt == 2) ? 0 : nxt + 1;
    }

    // coalesced flush of the sample buffer
    float* o = sample_xyz + (size_t)b * NS * 3;
    for (int i = tid; i < NS * 3; i += 256) o[i] = Samp[i];
}

// ---------------------------------------------------------------------------
// Kernel 2: ball query (first-64 in-radius indices, ascending) + feature
// gather. One 256-thread block per (b, s) centroid. Early-exit scan.
// d2 = na + nb - 2*dot; dot is an FMA CHAIN (XLA dot_general semantics),
// na/nb are non-FMA square-sums (XLA reduce semantics). VERIFIED rounds 2-12.
// ---------------------------------------------------------------------------
__global__ __launch_bounds__(256) void bq_gather_kernel(
    const float* __restrict__ xyz, const float* __restrict__ feat,
    const float* __restrict__ sample_xyz, float* __restrict__ out_feat)
{
    const int s   = blockIdx.x;
    const int b   = blockIdx.y;
    const int tid = threadIdx.x;

    __shared__ int   list[NK];
    __shared__ int   wavecnt[4];
    __shared__ float cen[3];

    if (tid < 3) cen[tid] = sample_xyz[((size_t)b * NS + s) * 3 + tid];
    __syncthreads();
    const float sx = cen[0], sy = cen[1], sz = cen[2];
    const float na = __fadd_rn(
        __fadd_rn(__fmul_rn(sx, sx), __fmul_rn(sy, sy)), __fmul_rn(sz, sz));
    const float* bxyz = xyz + (size_t)b * NPT * 3;

    int len = 0;
    for (int c0 = 0; c0 < NPT; c0 += 256) {
        const int idx = c0 + tid;
        const float x = bxyz[idx * 3 + 0];
        const float y = bxyz[idx * 3 + 1];
        const float z = bxyz[idx * 3 + 2];
        const float nb = __fadd_rn(
            __fadd_rn(__fmul_rn(x, x), __fmul_rn(y, y)), __fmul_rn(z, z));
        // dot as FMA chain (dot_general / matmul emitter semantics)
        const float dt = __fmaf_rn(sz, z, __fmaf_rn(sy, y, __fmul_rn(sx, x)));
        const float d2 = __fsub_rn(__fadd_rn(na, nb), __fmul_rn(2.0f, dt));
        const bool within = d2 < 0.04f;   // f32(0.2*0.2)

        const unsigned long long m = __ballot(within);
        const int wvq  = tid >> 6;
        const int lane = tid & 63;
        if (lane == 0) wavecnt[wvq] = __popcll(m);
        __syncthreads();
        const int w0 = wavecnt[0], w1 = wavecnt[1], w2 = wavecnt[2], w3 = wavecnt[3];
        int off = len;
        if (wvq > 0) off += w0;
        if (wvq > 1) off += w1;
        if (wvq > 2) off += w2;
        const int pre = __popcll(m & ((1ull << lane) - 1ull));
        const int pos = off + pre;
        if (within && pos < NK) list[pos] = idx;
        len += w0 + w1 + w2 + w3;
        __syncthreads();   // also orders list[] writes before gather reads
        if (len >= NK) break;
    }
    const int llen = len < NK ? len : NK;

    // gather: one wave per neighbor row (256 floats = 64 lanes x float4)
    const int lane = tid & 63;
    const int sub  = tid >> 6;   // 4 rows in flight per pass
    const float4* fbase = (const float4*)(feat + (size_t)b * NPT * NC);
    float4* obase = (float4*)(out_feat + (((size_t)b * NS + s) * (size_t)NK) * NC);
#pragma unroll
    for (int p = 0; p < NK / 4; ++p) {
        const int k   = p * 4 + sub;
        const int row = (k < llen) ? list[k] : NS;   // pad -> feat row 1024
        const float4 v = fbase[(size_t)row * (NC / 4) + lane];
        obase[(size_t)k * (NC / 4) + lane] = v;
    }
}

extern "C" void kernel_launch(void* const* d_in, const int* in_sizes, int n_in,
                              void* d_out, int out_size, void* d_ws, size_t ws_size,
                              hipStream_t stream) {
    const float* xyz  = (const float*)d_in[0];
    const float* feat = (const float*)d_in[1];
    float* out        = (float*)d_out;
    float* sample_xyz = out;                          // (B,S,3) = 12288 floats
    float* out_feat   = out + (size_t)NB * NS * 3;    // (B,S,K,C)

    fps_kernel<<<dim3(NB), dim3(256), 0, stream>>>(xyz, sample_xyz);
    bq_gather_kernel<<<dim3(NS, NB), dim3(256), 0, stream>>>(
        xyz, feat, sample_xyz, out_feat);
}

// Round 14
// 876.831 us; speedup vs baseline: 1.0981x; 1.0981x over previous
//
#include <hip/hip_runtime.h>
#include <cstdint>

#define NB   4      // batches
#define NPT  8192   // points
#define NC   256    // feature channels
#define NS   1024   // FPS samples
#define NK   64     // neighbors per ball
#define FPT  32     // points per thread in FPS (8192 / 256 threads)

typedef float v2f __attribute__((ext_vector_type(2)));

// ---------------------------------------------------------------------------
// DPP max step (f32, old=0 fill — safe: all reduced values >= 0).
// ---------------------------------------------------------------------------
template <int CTRL, int RMASK>
__device__ __forceinline__ float dpp_max_step(float x) {
    const int t = __builtin_amdgcn_update_dpp(
        0, __float_as_int(x), CTRL, RMASK, 0xf, false);
    return fmaxf(x, __int_as_float(t));
}
__device__ __forceinline__ float wave_max_f32(float x) {
    x = dpp_max_step<0x111, 0xf>(x);  // row_shr:1
    x = dpp_max_step<0x112, 0xf>(x);  // row_shr:2
    x = dpp_max_step<0x114, 0xf>(x);  // row_shr:4
    x = dpp_max_step<0x118, 0xf>(x);  // row_shr:8
    x = dpp_max_step<0x142, 0xa>(x);  // row_bcast:15 -> rows 1,3
    x = dpp_max_step<0x143, 0xc>(x);  // row_bcast:31 -> rows 2,3
    return x;                          // lane 63 holds wave max
}

// ---------------------------------------------------------------------------
// Kernel 1: farthest point sampling — FINAL FORM (= round 7, empirical best
// at 815 µs; six alternatives r8-r13 all regressed, see session journal).
// One 256-thread block (4 waves = 1 per SIMD) per batch.
// Structural floor (measured): step = ~1300 issue-cyc (source-irreducible;
// clang scalarizes v2f, pk-asm variants add marshalling movs) + ~600 cyc
// handshake (atomicMax+3-slot beats DPP-select, payload slots, spin-poll)
// = ~796 ns/step x 1024 steps.
// Handshake (VERIFIED r5/r7): delegate atomicMax's packed u64 key
// (valbits<<32 | 0xFFFFFFFF-idx) into a 3-slot rotating LDS buffer;
// post-barrier broadcast ds_read_b64; centroid re-fetch via 3 uniform b32
// reads. 3-slot zeroing proof: slot[nxt] was last read at step s-2
// post-barrier, which precedes barrier(s-1), which precedes tid0's zeroing
// at step s; the zero is ordered before step s+1's atomics by barrier(s).
// First-occurrence argmax (VERIFIED r1-r13): x-half = tid*32+0..15, y-half
// = tid*32+16..31; strict-> per half keeps earliest index; combine prefers
// x (all x indices < all y indices); lowest achieving lane via ballot+ffs
// (lanes own ascending contiguous index blocks); cross-wave via key max.
// NOTE: non-FMA left-to-right distance arithmetic (contract off) is VERIFIED
// bit-exact vs the reference. Do not "optimize" into FMA.
// ---------------------------------------------------------------------------
__global__ __launch_bounds__(256, 1) void fps_kernel(
    const float* __restrict__ xyz, float* __restrict__ sample_xyz)
{
    const int b   = blockIdx.x;
    const int tid = threadIdx.x;

    __shared__ float Xs[NPT], Ys[NPT], Zs[NPT];        // 96 KB SoA copy
    __shared__ float Samp[NS * 3];                     // 12 KB result buffer
    __shared__ unsigned long long slots[3];            // rotating winner slots

    const float* base = xyz + (size_t)b * NPT * 3;

    v2f px[16], py[16], pz[16], md[16];
#pragma unroll
    for (int j = 0; j < 16; ++j) {
        const int pa = tid * FPT + j;         // x-half point
        const int pb = tid * FPT + 16 + j;    // y-half point
        const float ax = base[pa * 3 + 0], ay = base[pa * 3 + 1], az = base[pa * 3 + 2];
        const float bx = base[pb * 3 + 0], by = base[pb * 3 + 1], bz = base[pb * 3 + 2];
        px[j] = (v2f){ax, bx};
        py[j] = (v2f){ay, by};
        pz[j] = (v2f){az, bz};
        md[j] = (v2f){__builtin_inff(), __builtin_inff()};
        Xs[pa] = ax; Ys[pa] = ay; Zs[pa] = az;
        Xs[pb] = bx; Ys[pb] = by; Zs[pb] = bz;
    }
    if (tid < 3) slots[tid] = 0ull;
    __syncthreads();

    int widx = 0;           // deterministic start at index 0 (matches reference)
    int cur = 0, nxt = 1;   // rotating slot indices (avoid % in the loop)
    for (int s = 0; s < NS; ++s) {
        // centroid xyz: uniform-address LDS broadcast reads
        const float sx = Xs[widx];
        const float sy = Ys[widx];
        const float sz = Zs[widx];
        if (tid == 0) {
            Samp[s * 3 + 0] = sx; Samp[s * 3 + 1] = sy; Samp[s * 3 + 2] = sz;
            slots[nxt] = 0ull;   // safe per 3-slot proof above
        }

        const v2f sxv = (v2f){sx, sx};
        const v2f syv = (v2f){sy, sy};
        const v2f szv = (v2f){sz, sz};

        v2f best2 = (v2f){-1.0f, -1.0f};
        int jx = 0, jy = 0;
        {
#pragma clang fp contract(off)
#pragma unroll
            for (int j = 0; j < 16; ++j) {
                // EXACT reference arithmetic per element:
                // ((dx*dx + dy*dy) + dz*dz), no FMA (contract off)
                const v2f dx = px[j] - sxv;
                const v2f dy = py[j] - syv;
                const v2f dz = pz[j] - szv;
                const v2f d  = (dx * dx + dy * dy) + dz * dz;
                const v2f m  = __builtin_elementwise_min(md[j], d);
                md[j] = m;
                // strict > keeps first occurrence within each half
                if (m.x > best2.x) jx = j;
                if (m.y > best2.y) jy = j;
                best2 = __builtin_elementwise_max(best2, m);
            }
        }
        // combine halves: every x-half index < every y-half index
        float    bestval;
        unsigned bestidx;
        if (best2.y > best2.x) { bestval = best2.y; bestidx = (unsigned)(tid * FPT + 16 + jy); }
        else                   { bestval = best2.x; bestidx = (unsigned)(tid * FPT + jx); }

        // wave max via DPP (VALU pipe), then first achieving lane via ballot
        const float wmax = wave_max_f32(bestval);
        const float smax = __int_as_float(
            __builtin_amdgcn_readlane(__float_as_int(wmax), 63));
        const unsigned long long msk = __ballot(bestval == smax);
        const int wl = __ffsll((long long)msk) - 1;          // lowest lane
        const unsigned widx_w =
            (unsigned)__builtin_amdgcn_readlane((int)bestidx, wl);
        if ((tid & 63) == 0) {
            const unsigned long long key =
                ((unsigned long long)__float_as_uint(smax) << 32)
                | (unsigned long long)(0xFFFFFFFFu - widx_w);
            atomicMax(&slots[cur], key);     // ds_max_u64, fire-and-forget
        }
        __syncthreads();

        // broadcast read of the winning key (b64 uniform — cheap)
        const unsigned long long best = slots[cur];
        widx = (int)(0xFFFFFFFFu - (unsigned)(best & 0xFFFFFFFFull));
        cur = nxt;
        nxt = (nxt == 2) ? 0 : nxt + 1;
    }

    // coalesced flush of the sample buffer
    float* o = sample_xyz + (size_t)b * NS * 3;
    for (int i = tid; i < NS * 3; i += 256) o[i] = Samp[i];
}

// ---------------------------------------------------------------------------
// Kernel 2: ball query (first-64 in-radius indices, ascending) + feature
// gather. One 256-thread block per (b, s) centroid. Early-exit scan.
// d2 = na + nb - 2*dot; dot is an FMA CHAIN (XLA dot_general semantics),
// na/nb are non-FMA square-sums (XLA reduce semantics). VERIFIED r2-r13.
// ~55 µs vs 43 µs pure-write floor (268 MB @ 6.3 TB/s).
// ---------------------------------------------------------------------------
__global__ __launch_bounds__(256) void bq_gather_kernel(
    const float* __restrict__ xyz, const float* __restrict__ feat,
    const float* __restrict__ sample_xyz, float* __restrict__ out_feat)
{
    const int s   = blockIdx.x;
    const int b   = blockIdx.y;
    const int tid = threadIdx.x;

    __shared__ int   list[NK];
    __shared__ int   wavecnt[4];
    __shared__ float cen[3];

    if (tid < 3) cen[tid] = sample_xyz[((size_t)b * NS + s) * 3 + tid];
    __syncthreads();
    const float sx = cen[0], sy = cen[1], sz = cen[2];
    const float na = __fadd_rn(
        __fadd_rn(__fmul_rn(sx, sx), __fmul_rn(sy, sy)), __fmul_rn(sz, sz));
    const float* bxyz = xyz + (size_t)b * NPT * 3;

    int len = 0;
    for (int c0 = 0; c0 < NPT; c0 += 256) {
        const int idx = c0 + tid;
        const float x = bxyz[idx * 3 + 0];
        const float y = bxyz[idx * 3 + 1];
        const float z = bxyz[idx * 3 + 2];
        const float nb = __fadd_rn(
            __fadd_rn(__fmul_rn(x, x), __fmul_rn(y, y)), __fmul_rn(z, z));
        // dot as FMA chain (dot_general / matmul emitter semantics)
        const float dt = __fmaf_rn(sz, z, __fmaf_rn(sy, y, __fmul_rn(sx, x)));
        const float d2 = __fsub_rn(__fadd_rn(na, nb), __fmul_rn(2.0f, dt));
        const bool within = d2 < 0.04f;   // f32(0.2*0.2)

        const unsigned long long m = __ballot(within);
        const int wvq  = tid >> 6;
        const int lane = tid & 63;
        if (lane == 0) wavecnt[wvq] = __popcll(m);
        __syncthreads();
        const int w0 = wavecnt[0], w1 = wavecnt[1], w2 = wavecnt[2], w3 = wavecnt[3];
        int off = len;
        if (wvq > 0) off += w0;
        if (wvq > 1) off += w1;
        if (wvq > 2) off += w2;
        const int pre = __popcll(m & ((1ull << lane) - 1ull));
        const int pos = off + pre;
        if (within && pos < NK) list[pos] = idx;
        len += w0 + w1 + w2 + w3;
        __syncthreads();   // also orders list[] writes before gather reads
        if (len >= NK) break;
    }
    const int llen = len < NK ? len : NK;

    // gather: one wave per neighbor row (256 floats = 64 lanes x float4)
    const int lane = tid & 63;
    const int sub  = tid >> 6;   // 4 rows in flight per pass
    const float4* fbase = (const float4*)(feat + (size_t)b * NPT * NC);
    float4* obase = (float4*)(out_feat + (((size_t)b * NS + s) * (size_t)NK) * NC);
#pragma unroll
    for (int p = 0; p < NK / 4; ++p) {
        const int k   = p * 4 + sub;
        const int row = (k < llen) ? list[k] : NS;   // pad -> feat row 1024
        const float4 v = fbase[(size_t)row * (NC / 4) + lane];
        obase[(size_t)k * (NC / 4) + lane] = v;
    }
}

extern "C" void kernel_launch(void* const* d_in, const int* in_sizes, int n_in,
                              void* d_out, int out_size, void* d_ws, size_t ws_size,
                              hipStream_t stream) {
    const float* xyz  = (const float*)d_in[0];
    const float* feat = (const float*)d_in[1];
    float* out        = (float*)d_out;
    float* sample_xyz = out;                          // (B,S,3) = 12288 floats
    float* out_feat   = out + (size_t)NB * NS * 3;    // (B,S,K,C)

    fps_kernel<<<dim3(NB), dim3(256), 0, stream>>>(xyz, sample_xyz);
    bq_gather_kernel<<<dim3(NS, NB), dim3(256), 0, stream>>>(
        xyz, feat, sample_xyz, out_feat);
}